// Round 7
// baseline (314.079 us; speedup 1.0000x reference)
//
#include <hip/hip_runtime.h>

#define TS 524288u          // 2^19
#define PRIME 2654435761u
#define NPTS 1048576u
#define MASK (TS - 1u)
#define NBUK 4096u          // 64x64 spatial buckets
#define CAP 320u            // bucket capacity: lambda=256, +4 sigma; overflow handled
#define OVF_CAP 8192u

// ---- ws layout (bytes); total 15.86 MB < 16.79 MB proven available ----
#define WS_CURSOR   0u          // u32[4096]          = 16384
#define WS_OVFCNT   16384u      // u32 (padded)
#define WS_OVF_XY   16640u      // float2[8192]       = 65536
#define WS_OVF_IDX  82176u      // u32[8192]          = 32768
#define WS_XYBUF    131072u     // float2[4096*320]   = 10485760
#define WS_IDXBUF   10616832u   // u32[4096*320]      = 5242880
#define WS_NEED     15859712u

typedef float vfloat4 __attribute__((ext_vector_type(4)));

// floor(16 * fl32(g)^l), g = 64^(1/15); fl32(g) rounds UP so the exact-integer
// levels (5,10,15) floor to 64/256/1024 under correctly-rounded powf (= numpy).
__device__ __constant__ float c_scale[16] = {
    16.f, 21.f, 27.f, 36.f, 48.f, 64.f, 84.f, 111.f,
    147.f, 194.f, 256.f, 337.f, 445.f, 588.f, 776.f, 1024.f
};

// Staged levels 0-3 (res 16,21,27,36 -> grid widths 17,22,28,37).
#define W0 17
#define W1 22
#define W2 28
#define W3 37
#define B0 0
#define B1 (B0 + W0*W0)        // 289
#define B2 (B1 + W1*W1)        // 773
#define B3 (B2 + W2*W2)        // 1557
#define NSTAGE (B3 + W3*W3)    // 2926 float2 = 23408 B

__device__ __forceinline__ unsigned bucket_of(float2 xy) {
    unsigned bx = (unsigned)(xy.x * 64.0f); if (bx > 63u) bx = 63u;
    unsigned by = (unsigned)(xy.y * 64.0f); if (by > 63u) by = 63u;
    return by * 64u + bx;
}

// Shared bilinear tap: one level, global table.
__device__ __forceinline__ void enc_level(
    float2 xy, unsigned l, const float2* __restrict__ tab,
    float& ex, float& ey)
{
    float s = c_scale[l];
    float sx = xy.x * s, sy = xy.y * s;
    float fxf = floorf(sx), fyf = floorf(sy);
    float cxf = ceilf(sx),  cyf = ceilf(sy);
    float ox = sx - fxf, oy = sy - fyf;
    unsigned fx = (unsigned)(int)fxf, fy = (unsigned)(int)fyf;
    unsigned cx = (unsigned)(int)cxf, cy = (unsigned)(int)cyf;
    unsigned hcy = cy * PRIME, hfy = fy * PRIME;
    unsigned base = l << 19;
    float2 f0 = tab[((cx ^ hcy) & MASK) | base];
    float2 f1 = tab[((cx ^ hfy) & MASK) | base];
    float2 f2 = tab[((fx ^ hcy) & MASK) | base];
    float2 f3 = tab[((fx ^ hfy) & MASK) | base];
    float wox = 1.0f - ox, woy = 1.0f - oy;
    float f03x = f0.x * ox + f3.x * wox;
    float f03y = f0.y * ox + f3.y * wox;
    float f12x = f1.x * ox + f2.x * wox;
    float f12y = f1.y * ox + f2.y * wox;
    ex = f03x * oy + f12x * woy;
    ey = f03y * oy + f12y * woy;
}

// ---- Pass 0: init cursors (cursor[b] = b*CAP) + overflow counter ----
__global__ __launch_bounds__(256) void init_kernel(
    unsigned* __restrict__ cursor, unsigned* __restrict__ ovf_cnt)
{
    unsigned t = blockIdx.x * 256u + threadIdx.x;
    if (t < NBUK) cursor[t] = t * CAP;
    if (t == 0u) *ovf_cnt = 0u;
}

// ---- Pass 1: fused LDS-privatized counting sort into fixed-cap regions ----
// 1024 blocks x 1024-point chunks (was 256x4096 = 1 block/CU, latency-bound
// at 4 waves/CU). Packed base|take halves LDS to 32KB -> 4 blocks/CU,
// 16 waves/CU. Global atomics stay aggregated (one per block-nonempty bin).
__global__ __launch_bounds__(256) void sort_kernel(
    const float2* __restrict__ x,
    unsigned* __restrict__ cursor,
    unsigned* __restrict__ ovf_cnt,
    float2* __restrict__ ovf_xy,
    unsigned* __restrict__ ovf_idx,
    float2* __restrict__ xybuf,
    unsigned* __restrict__ idxbuf)
{
    __shared__ unsigned lhist[NBUK];      // counts, then running local offsets
    __shared__ unsigned lbase_cap[NBUK];  // (reserved base << 9) | granted take
    unsigned tid = threadIdx.x;
    unsigned cbase = blockIdx.x * 1024u;

    for (unsigned j = tid; j < NBUK; j += 256u) lhist[j] = 0u;
    __syncthreads();

    float2 pxy[4];
#pragma unroll
    for (int k = 0; k < 4; ++k) {
        float2 xy = x[cbase + tid + (unsigned)k * 256u];
        pxy[k] = xy;
        atomicAdd(&lhist[bucket_of(xy)], 1u);
    }
    __syncthreads();

    for (unsigned j = tid; j < NBUK; j += 256u) {
        unsigned c = lhist[j];
        unsigned base = 0u, take = 0u;
        if (c) {
            base = atomicAdd(&cursor[j], c);
            unsigned prior = base - j * CAP;
            unsigned avail = (prior >= CAP) ? 0u : (CAP - prior);
            take = (c < avail) ? c : avail;
        }
        // base < 2.4M < 2^22, take <= 320 < 2^9 -> pack fits 31 bits
        lbase_cap[j] = (base << 9) | take;
        lhist[j] = 0u;                 // reuse as running local offset
    }
    __syncthreads();

#pragma unroll
    for (int k = 0; k < 4; ++k) {
        float2 xy = pxy[k];
        unsigned b = bucket_of(xy);
        unsigned idx = cbase + tid + (unsigned)k * 256u;
        unsigned loff = atomicAdd(&lhist[b], 1u);
        unsigned bc = lbase_cap[b];
        unsigned take = bc & 511u;
        if (loff < take) {
            unsigned pos = (bc >> 9) + loff;
            xybuf[pos] = xy;
            idxbuf[pos] = idx;
        } else {
            unsigned o = atomicAdd(ovf_cnt, 1u);
            if (o < OVF_CAP) { ovf_xy[o] = xy; ovf_idx[o] = idx; }
        }
    }
}

// ---- Pass 2: encode. 512 threads = 8 waves = 8 buckets per block.
// Levels 0-3 staged in LDS (TA-pipe offload, proven +15us r5->r6).
// NOTE: encode is TA-line-rate saturated — 92us at both 16 and 24 waves/CU. ----
__global__ __launch_bounds__(512) void encode_kernel(
    const float2* __restrict__ xybuf,
    const unsigned* __restrict__ idxbuf,
    const unsigned* __restrict__ cursor,
    const float2* __restrict__ tab,
    vfloat4* __restrict__ out)
{
    __shared__ float2 lds[NSTAGE];
    unsigned tid = threadIdx.x;

#define STAGE(L, W, B)                                                  \
    for (unsigned i = tid; i < (unsigned)((W)*(W)); i += 512u) {        \
        unsigned vy = i / (unsigned)(W), vx = i % (unsigned)(W);        \
        unsigned h = ((vx ^ (vy * PRIME)) & MASK) | ((unsigned)(L) << 19); \
        lds[(B) + i] = tab[h];                                          \
    }
    STAGE(0, W0, B0)
    STAGE(1, W1, B1)
    STAGE(2, W2, B2)
    STAGE(3, W3, B3)
#undef STAGE
    __syncthreads();

    unsigned wave = tid >> 6;              // 0..7: bucket within block
    unsigned lane = tid & 63u;
    unsigned lq   = lane & 3u;             // level quad: levels 4lq..4lq+3
    unsigned s0   = lane >> 2;             // 0..15: slot within iteration
    unsigned b    = blockIdx.x * 8u + wave;
    unsigned total = cursor[b] - b * CAP;
    unsigned cnt  = (total < CAP) ? total : CAP;
    unsigned l0   = lq << 2;
    unsigned pbase = b * CAP;

    const unsigned Wk[4] = { W0, W1, W2, W3 };
    const unsigned Bk[4] = { B0, B1, B2, B3 };

    for (unsigned s = s0; s < cnt; s += 16u) {
        float2 xy   = xybuf[pbase + s];
        unsigned idx = idxbuf[pbase + s];
        vfloat4 r[2];

        if (lq == 0u) {
            // levels 0-3 from LDS
#pragma unroll
            for (int k = 0; k < 4; ++k) {
                float sc = c_scale[k];
                float sx = xy.x * sc, sy = xy.y * sc;
                float fxf = floorf(sx), fyf = floorf(sy);
                float cxf = ceilf(sx),  cyf = ceilf(sy);
                float ox = sx - fxf, oy = sy - fyf;
                unsigned fx = (unsigned)(int)fxf, fy = (unsigned)(int)fyf;
                unsigned cx = (unsigned)(int)cxf, cy = (unsigned)(int)cyf;
                unsigned w = Wk[k], bb = Bk[k];
                float2 f0 = lds[bb + cy * w + cx];
                float2 f1 = lds[bb + fy * w + cx];
                float2 f2 = lds[bb + cy * w + fx];
                float2 f3 = lds[bb + fy * w + fx];
                float wox = 1.0f - ox, woy = 1.0f - oy;
                float f03x = f0.x * ox + f3.x * wox;
                float f03y = f0.y * ox + f3.y * wox;
                float f12x = f1.x * ox + f2.x * wox;
                float f12y = f1.y * ox + f2.y * wox;
                float ex = f03x * oy + f12x * woy;
                float ey = f03y * oy + f12y * woy;
                if ((k & 1) == 0) { r[k >> 1].x = ex; r[k >> 1].y = ey; }
                else              { r[k >> 1].z = ex; r[k >> 1].w = ey; }
            }
        } else {
            // levels 4lq..4lq+3 from global
#pragma unroll
            for (int k = 0; k < 4; ++k) {
                float ex, ey;
                enc_level(xy, l0 + (unsigned)k, tab, ex, ey);
                if ((k & 1) == 0) { r[k >> 1].x = ex; r[k >> 1].y = ey; }
                else              { r[k >> 1].z = ex; r[k >> 1].w = ey; }
            }
        }

        // 4 lq-threads of one point cover idx*8..idx*8+7: one aligned,
        // fully-written 128B record (2 lines) -> no write amplification.
        unsigned o = idx * 8u + lq * 2u;
        __builtin_nontemporal_store(r[0], &out[o]);
        __builtin_nontemporal_store(r[1], &out[o + 1]);
    }
}

// ---- Pass 3: encode overflow points directly (expected ~0-100 points) ----
__global__ __launch_bounds__(256) void fixup_kernel(
    const unsigned* __restrict__ ovf_cnt,
    const float2* __restrict__ ovf_xy,
    const unsigned* __restrict__ ovf_idx,
    const float2* __restrict__ tab,
    vfloat4* __restrict__ out)
{
    unsigned n = *ovf_cnt; if (n > OVF_CAP) n = OVF_CAP;
    unsigned stride = gridDim.x * 256u;
    for (unsigned p = blockIdx.x * 256u + threadIdx.x; p < n; p += stride) {
        float2 xy = ovf_xy[p];
        unsigned idx = ovf_idx[p];
        vfloat4 acc[8];
#pragma unroll
        for (int l = 0; l < 16; ++l) {
            float ex, ey;
            enc_level(xy, (unsigned)l, tab, ex, ey);
            if ((l & 1) == 0) { acc[l >> 1].x = ex; acc[l >> 1].y = ey; }
            else              { acc[l >> 1].z = ex; acc[l >> 1].w = ey; }
        }
#pragma unroll
        for (int q = 0; q < 8; ++q) out[idx * 8u + (unsigned)q] = acc[q];
    }
}

// ---- Fallback: proven round-0 unsorted kernel (ws too small; never expected) ----
__global__ __launch_bounds__(256) void hashenc_kernel(
    const float2* __restrict__ x,
    const float2* __restrict__ tab,
    vfloat4* __restrict__ out,
    unsigned pts_per_block)
{
    __shared__ float2 lds[NSTAGE];
    unsigned tid = threadIdx.x;

#define STAGE(L, W, B)                                                  \
    for (unsigned i = tid; i < (unsigned)((W)*(W)); i += 256u) {        \
        unsigned vy = i / (unsigned)(W), vx = i % (unsigned)(W);        \
        unsigned h = ((vx ^ (vy * PRIME)) & MASK) | ((unsigned)(L) << 19); \
        lds[(B) + i] = tab[h];                                          \
    }
    STAGE(0, W0, B0)
    STAGE(1, W1, B1)
    STAGE(2, W2, B2)
    STAGE(3, W3, B3)
#undef STAGE
    __syncthreads();

    const unsigned lq = tid & 3u;
    const unsigned lane_p = tid >> 2;
    const unsigned l0 = lq << 2;
    const unsigned bs = blockIdx.x * pts_per_block;
    unsigned be = bs + pts_per_block;
    if (be > NPTS) be = NPTS;

    const unsigned Wk[4] = { W0, W1, W2, W3 };
    const unsigned Bk[4] = { B0, B1, B2, B3 };

    for (unsigned p = bs + lane_p; p < be; p += 64u) {
        float2 xy = x[p];
        vfloat4 r[2];

        if (lq == 0u) {
#pragma unroll
            for (int k = 0; k < 4; ++k) {
                float s = c_scale[k];
                float sx = xy.x * s, sy = xy.y * s;
                float fxf = floorf(sx), fyf = floorf(sy);
                float cxf = ceilf(sx),  cyf = ceilf(sy);
                float ox = sx - fxf, oy = sy - fyf;
                unsigned fx = (unsigned)(int)fxf, fy = (unsigned)(int)fyf;
                unsigned cx = (unsigned)(int)cxf, cy = (unsigned)(int)cyf;
                unsigned w = Wk[k], b = Bk[k];
                float2 f0 = lds[b + cy * w + cx];
                float2 f1 = lds[b + fy * w + cx];
                float2 f2 = lds[b + cy * w + fx];
                float2 f3 = lds[b + fy * w + fx];
                float wox = 1.0f - ox, woy = 1.0f - oy;
                float f03x = f0.x * ox + f3.x * wox;
                float f03y = f0.y * ox + f3.y * wox;
                float f12x = f1.x * ox + f2.x * wox;
                float f12y = f1.y * ox + f2.y * wox;
                float ex = f03x * oy + f12x * woy;
                float ey = f03y * oy + f12y * woy;
                if ((k & 1) == 0) { r[k >> 1].x = ex; r[k >> 1].y = ey; }
                else              { r[k >> 1].z = ex; r[k >> 1].w = ey; }
            }
        } else {
#pragma unroll
            for (int k = 0; k < 4; ++k) {
                float ex, ey;
                enc_level(xy, l0 + (unsigned)k, tab, ex, ey);
                if ((k & 1) == 0) { r[k >> 1].x = ex; r[k >> 1].y = ey; }
                else              { r[k >> 1].z = ex; r[k >> 1].w = ey; }
            }
        }

        unsigned o = p * 8u + lq * 2u;
        __builtin_nontemporal_store(r[0], &out[o]);
        __builtin_nontemporal_store(r[1], &out[o + 1]);
    }
}

extern "C" void kernel_launch(void* const* d_in, const int* in_sizes, int n_in,
                              void* d_out, int out_size, void* d_ws, size_t ws_size,
                              hipStream_t stream)
{
    const float2* x   = (const float2*)d_in[0];
    const float2* tab = (const float2*)d_in[1];
    vfloat4* out = (vfloat4*)d_out;

    if (d_ws != nullptr && ws_size >= (size_t)WS_NEED) {
        char* ws = (char*)d_ws;
        unsigned* cursor  = (unsigned*)(ws + WS_CURSOR);
        unsigned* ovf_cnt = (unsigned*)(ws + WS_OVFCNT);
        float2*   ovf_xy  = (float2*)  (ws + WS_OVF_XY);
        unsigned* ovf_idx = (unsigned*)(ws + WS_OVF_IDX);
        float2*   xybuf   = (float2*)  (ws + WS_XYBUF);
        unsigned* idxbuf  = (unsigned*)(ws + WS_IDXBUF);

        init_kernel<<<16, 256, 0, stream>>>(cursor, ovf_cnt);
        sort_kernel<<<1024, 256, 0, stream>>>(x, cursor, ovf_cnt, ovf_xy,
                                              ovf_idx, xybuf, idxbuf);
        encode_kernel<<<NBUK / 8, 512, 0, stream>>>(xybuf, idxbuf, cursor, tab, out);
        fixup_kernel<<<8, 256, 0, stream>>>(ovf_cnt, ovf_xy, ovf_idx, tab, out);
    } else {
        const unsigned n_blocks = 1536u;
        const unsigned ppb = (NPTS + n_blocks - 1u) / n_blocks;
        hashenc_kernel<<<n_blocks, 256, 0, stream>>>(x, tab, out, ppb);
    }
}

// Round 8
// 277.330 us; speedup vs baseline: 1.1325x; 1.1325x over previous
//
#include <hip/hip_runtime.h>

#define TS 524288u          // 2^19
#define PRIME 2654435761u
#define NPTS 1048576u
#define MASK (TS - 1u)
#define NBUK 4096u          // 64x64 spatial buckets
#define CAP 320u            // bucket capacity: lambda=256, +4 sigma; overflow handled
#define OVF_CAP 8192u

// ---- ws layout (bytes); total 15.86 MB < 16.79 MB proven available ----
#define WS_CURSOR   0u          // u32[4096]          = 16384
#define WS_OVFCNT   16384u      // u32 (padded)
#define WS_OVF_XY   16640u      // float2[8192]       = 65536
#define WS_OVF_IDX  82176u      // u32[8192]          = 32768
#define WS_XYBUF    131072u     // float2[4096*320]   = 10485760
#define WS_IDXBUF   10616832u   // u32[4096*320]      = 5242880
#define WS_NEED     15859712u

typedef float vfloat4 __attribute__((ext_vector_type(4)));

// floor(16 * fl32(g)^l), g = 64^(1/15); fl32(g) rounds UP so the exact-integer
// levels (5,10,15) floor to 64/256/1024 under correctly-rounded powf (= numpy).
__device__ __constant__ float c_scale[16] = {
    16.f, 21.f, 27.f, 36.f, 48.f, 64.f, 84.f, 111.f,
    147.f, 194.f, 256.f, 337.f, 445.f, 588.f, 776.f, 1024.f
};

// Staged levels 0-3 (res 16,21,27,36 -> grid widths 17,22,28,37).
#define W0 17
#define W1 22
#define W2 28
#define W3 37
#define B0 0
#define B1 (B0 + W0*W0)        // 289
#define B2 (B1 + W1*W1)        // 773
#define B3 (B2 + W2*W2)        // 1557
#define NSTAGE (B3 + W3*W3)    // 2926 float2 = 23408 B

__device__ __forceinline__ unsigned bucket_of(float2 xy) {
    unsigned bx = (unsigned)(xy.x * 64.0f); if (bx > 63u) bx = 63u;
    unsigned by = (unsigned)(xy.y * 64.0f); if (by > 63u) by = 63u;
    return by * 64u + bx;
}

// Shared bilinear tap: one level, global table (plain 4x float2 gathers).
__device__ __forceinline__ void enc_level(
    float2 xy, unsigned l, const float2* __restrict__ tab,
    float& ex, float& ey)
{
    float s = c_scale[l];
    float sx = xy.x * s, sy = xy.y * s;
    float fxf = floorf(sx), fyf = floorf(sy);
    float cxf = ceilf(sx),  cyf = ceilf(sy);
    float ox = sx - fxf, oy = sy - fyf;
    unsigned fx = (unsigned)(int)fxf, fy = (unsigned)(int)fyf;
    unsigned cx = (unsigned)(int)cxf, cy = (unsigned)(int)cyf;
    unsigned hcy = cy * PRIME, hfy = fy * PRIME;
    unsigned base = l << 19;
    float2 f0 = tab[((cx ^ hcy) & MASK) | base];
    float2 f1 = tab[((cx ^ hfy) & MASK) | base];
    float2 f2 = tab[((fx ^ hcy) & MASK) | base];
    float2 f3 = tab[((fx ^ hfy) & MASK) | base];
    float wox = 1.0f - ox, woy = 1.0f - oy;
    float f03x = f0.x * ox + f3.x * wox;
    float f03y = f0.y * ox + f3.y * wox;
    float f12x = f1.x * ox + f2.x * wox;
    float f12y = f1.y * ox + f2.y * wox;
    ex = f03x * oy + f12x * woy;
    ey = f03y * oy + f12y * woy;
}

// ---- Pass 0: init cursors (cursor[b] = b*CAP) + overflow counter ----
__global__ __launch_bounds__(256) void init_kernel(
    unsigned* __restrict__ cursor, unsigned* __restrict__ ovf_cnt)
{
    unsigned t = blockIdx.x * 256u + threadIdx.x;
    if (t < NBUK) cursor[t] = t * CAP;
    if (t == 0u) *ovf_cnt = 0u;
}

// ---- Pass 1: fused LDS-privatized counting sort into fixed-cap regions ----
// 256 blocks x 4096-pt chunks (proven-cheap geometry: bin overhead and
// aggregated atomics scale with blocks*NBUK; r7's 1024-block split regressed).
// 512 threads/block: per-thread bin sweeps halve (8 iters), 8 waves/CU.
__global__ __launch_bounds__(512) void sort_kernel(
    const float2* __restrict__ x,
    unsigned* __restrict__ cursor,
    unsigned* __restrict__ ovf_cnt,
    float2* __restrict__ ovf_xy,
    unsigned* __restrict__ ovf_idx,
    float2* __restrict__ xybuf,
    unsigned* __restrict__ idxbuf)
{
    __shared__ unsigned lhist[NBUK];      // counts, then running local offsets
    __shared__ unsigned lbase_cap[NBUK];  // (reserved base << 9) | granted take
    unsigned tid = threadIdx.x;
    unsigned cbase = blockIdx.x * 4096u;

    for (unsigned j = tid; j < NBUK; j += 512u) lhist[j] = 0u;
    __syncthreads();

    float2 pxy[8];
#pragma unroll
    for (int k = 0; k < 8; ++k) {
        float2 xy = x[cbase + tid + (unsigned)k * 512u];
        pxy[k] = xy;
        atomicAdd(&lhist[bucket_of(xy)], 1u);
    }
    __syncthreads();

    for (unsigned j = tid; j < NBUK; j += 512u) {
        unsigned c = lhist[j];
        unsigned base = 0u, take = 0u;
        if (c) {
            base = atomicAdd(&cursor[j], c);
            unsigned prior = base - j * CAP;
            unsigned avail = (prior >= CAP) ? 0u : (CAP - prior);
            take = (c < avail) ? c : avail;
        }
        // base < 2.4M < 2^22, take <= 320 < 2^9 -> pack fits 31 bits
        lbase_cap[j] = (base << 9) | take;
        lhist[j] = 0u;                 // reuse as running local offset
    }
    __syncthreads();

#pragma unroll
    for (int k = 0; k < 8; ++k) {
        float2 xy = pxy[k];
        unsigned b = bucket_of(xy);
        unsigned idx = cbase + tid + (unsigned)k * 512u;
        unsigned loff = atomicAdd(&lhist[b], 1u);
        unsigned bc = lbase_cap[b];
        unsigned take = bc & 511u;
        if (loff < take) {
            unsigned pos = (bc >> 9) + loff;
            xybuf[pos] = xy;
            idxbuf[pos] = idx;
        } else {
            unsigned o = atomicAdd(ovf_cnt, 1u);
            if (o < OVF_CAP) { ovf_xy[o] = xy; ovf_idx[o] = idx; }
        }
    }
}

// ---- Pass 2: encode. 512 threads = 8 waves = 8 buckets per block.
// Levels 0-3 in LDS (TA offload, proven). Global levels use PAIR-MERGED
// corner loads: i0^i2 == i1^i3 == cx^fx; when cx^fx<=1 one aligned float4
// serves both x-corners of a y-row. In the current TA-throughput-bound
// regime (92us at 16 AND 24 waves/CU) this cuts gather instrs ~25%.
// (Round-2 null was in a latency-bound regime — different limiter.) ----
__global__ __launch_bounds__(512) void encode_kernel(
    const float2* __restrict__ xybuf,
    const unsigned* __restrict__ idxbuf,
    const unsigned* __restrict__ cursor,
    const float2* __restrict__ tab,
    vfloat4* __restrict__ out)
{
    __shared__ float2 lds[NSTAGE];
    unsigned tid = threadIdx.x;

#define STAGE(L, W, B)                                                  \
    for (unsigned i = tid; i < (unsigned)((W)*(W)); i += 512u) {        \
        unsigned vy = i / (unsigned)(W), vx = i % (unsigned)(W);        \
        unsigned h = ((vx ^ (vy * PRIME)) & MASK) | ((unsigned)(L) << 19); \
        lds[(B) + i] = tab[h];                                          \
    }
    STAGE(0, W0, B0)
    STAGE(1, W1, B1)
    STAGE(2, W2, B2)
    STAGE(3, W3, B3)
#undef STAGE
    __syncthreads();

    const vfloat4* __restrict__ tab4 = (const vfloat4*)tab;  // aligned pairs

    unsigned wave = tid >> 6;              // 0..7: bucket within block
    unsigned lane = tid & 63u;
    unsigned lq   = lane & 3u;             // level quad: levels 4lq..4lq+3
    unsigned s0   = lane >> 2;             // 0..15: slot within iteration
    unsigned b    = blockIdx.x * 8u + wave;
    unsigned total = cursor[b] - b * CAP;
    unsigned cnt  = (total < CAP) ? total : CAP;
    unsigned l0   = lq << 2;
    unsigned pbase = b * CAP;

    const unsigned Wk[4] = { W0, W1, W2, W3 };
    const unsigned Bk[4] = { B0, B1, B2, B3 };

    for (unsigned s = s0; s < cnt; s += 16u) {
        float2 xy   = xybuf[pbase + s];
        unsigned idx = idxbuf[pbase + s];
        vfloat4 r[2];

        if (lq == 0u) {
            // levels 0-3 from LDS
#pragma unroll
            for (int k = 0; k < 4; ++k) {
                float sc = c_scale[k];
                float sx = xy.x * sc, sy = xy.y * sc;
                float fxf = floorf(sx), fyf = floorf(sy);
                float cxf = ceilf(sx),  cyf = ceilf(sy);
                float ox = sx - fxf, oy = sy - fyf;
                unsigned fx = (unsigned)(int)fxf, fy = (unsigned)(int)fyf;
                unsigned cx = (unsigned)(int)cxf, cy = (unsigned)(int)cyf;
                unsigned w = Wk[k], bb = Bk[k];
                float2 f0 = lds[bb + cy * w + cx];
                float2 f1 = lds[bb + fy * w + cx];
                float2 f2 = lds[bb + cy * w + fx];
                float2 f3 = lds[bb + fy * w + fx];
                float wox = 1.0f - ox, woy = 1.0f - oy;
                float f03x = f0.x * ox + f3.x * wox;
                float f03y = f0.y * ox + f3.y * wox;
                float f12x = f1.x * ox + f2.x * wox;
                float f12y = f1.y * ox + f2.y * wox;
                float ex = f03x * oy + f12x * woy;
                float ey = f03y * oy + f12y * woy;
                if ((k & 1) == 0) { r[k >> 1].x = ex; r[k >> 1].y = ey; }
                else              { r[k >> 1].z = ex; r[k >> 1].w = ey; }
            }
        } else {
            // levels 4lq..4lq+3 from global, pair-merged
#pragma unroll
            for (int k = 0; k < 4; ++k) {
                unsigned l = l0 + (unsigned)k;
                float sc = c_scale[l];
                float sx = xy.x * sc, sy = xy.y * sc;
                float fxf = floorf(sx), fyf = floorf(sy);
                float cxf = ceilf(sx),  cyf = ceilf(sy);
                float ox = sx - fxf, oy = sy - fyf;
                unsigned fx = (unsigned)(int)fxf, fy = (unsigned)(int)fyf;
                unsigned cx = (unsigned)(int)cxf, cy = (unsigned)(int)cyf;
                unsigned hcy = cy * PRIME, hfy = fy * PRIME;
                unsigned i0 = (cx ^ hcy) & MASK;   // (cx, cy)
                unsigned i1 = (cx ^ hfy) & MASK;   // (cx, fy)
                unsigned i2 = (fx ^ hcy) & MASK;   // (fx, cy)
                unsigned i3 = (fx ^ hfy) & MASK;   // (fx, fy)
                unsigned base4 = l << 18;          // float4-granule level base
                vfloat4 qt = tab4[base4 + (i2 >> 1)];   // row y=cy pair
                vfloat4 qb = tab4[base4 + (i3 >> 1)];   // row y=fy pair
                float f2x = (i2 & 1u) ? qt.z : qt.x;
                float f2y = (i2 & 1u) ? qt.w : qt.y;
                float f3x = (i3 & 1u) ? qb.z : qb.x;
                float f3y = (i3 & 1u) ? qb.w : qb.y;
                float f0x, f0y, f1x, f1y;
                if ((cx ^ fx) <= 1u) {
                    // x-corners share the aligned pair already in qt/qb
                    f0x = (i0 & 1u) ? qt.z : qt.x;
                    f0y = (i0 & 1u) ? qt.w : qt.y;
                    f1x = (i1 & 1u) ? qb.z : qb.x;
                    f1y = (i1 & 1u) ? qb.w : qb.y;
                } else {
                    // straddling pair: exec-masked lanes issue the extra loads
                    float2 f0 = tab[(l << 19) | i0];
                    float2 f1 = tab[(l << 19) | i1];
                    f0x = f0.x; f0y = f0.y;
                    f1x = f1.x; f1y = f1.y;
                }
                float wox = 1.0f - ox, woy = 1.0f - oy;
                float f03x = f0x * ox + f3x * wox;
                float f03y = f0y * ox + f3y * wox;
                float f12x = f1x * ox + f2x * wox;
                float f12y = f1y * ox + f2y * wox;
                float ex = f03x * oy + f12x * woy;
                float ey = f03y * oy + f12y * woy;
                if ((k & 1) == 0) { r[k >> 1].x = ex; r[k >> 1].y = ey; }
                else              { r[k >> 1].z = ex; r[k >> 1].w = ey; }
            }
        }

        // 4 lq-threads of one point cover idx*8..idx*8+7: one aligned,
        // fully-written 128B record (2 lines) -> no write amplification.
        unsigned o = idx * 8u + lq * 2u;
        __builtin_nontemporal_store(r[0], &out[o]);
        __builtin_nontemporal_store(r[1], &out[o + 1]);
    }
}

// ---- Pass 3: encode overflow points directly (expected ~0-100 points) ----
__global__ __launch_bounds__(256) void fixup_kernel(
    const unsigned* __restrict__ ovf_cnt,
    const float2* __restrict__ ovf_xy,
    const unsigned* __restrict__ ovf_idx,
    const float2* __restrict__ tab,
    vfloat4* __restrict__ out)
{
    unsigned n = *ovf_cnt; if (n > OVF_CAP) n = OVF_CAP;
    unsigned stride = gridDim.x * 256u;
    for (unsigned p = blockIdx.x * 256u + threadIdx.x; p < n; p += stride) {
        float2 xy = ovf_xy[p];
        unsigned idx = ovf_idx[p];
        vfloat4 acc[8];
#pragma unroll
        for (int l = 0; l < 16; ++l) {
            float ex, ey;
            enc_level(xy, (unsigned)l, tab, ex, ey);
            if ((l & 1) == 0) { acc[l >> 1].x = ex; acc[l >> 1].y = ey; }
            else              { acc[l >> 1].z = ex; acc[l >> 1].w = ey; }
        }
#pragma unroll
        for (int q = 0; q < 8; ++q) out[idx * 8u + (unsigned)q] = acc[q];
    }
}

// ---- Fallback: proven round-0 unsorted kernel (ws too small; never expected) ----
__global__ __launch_bounds__(256) void hashenc_kernel(
    const float2* __restrict__ x,
    const float2* __restrict__ tab,
    vfloat4* __restrict__ out,
    unsigned pts_per_block)
{
    __shared__ float2 lds[NSTAGE];
    unsigned tid = threadIdx.x;

#define STAGE(L, W, B)                                                  \
    for (unsigned i = tid; i < (unsigned)((W)*(W)); i += 256u) {        \
        unsigned vy = i / (unsigned)(W), vx = i % (unsigned)(W);        \
        unsigned h = ((vx ^ (vy * PRIME)) & MASK) | ((unsigned)(L) << 19); \
        lds[(B) + i] = tab[h];                                          \
    }
    STAGE(0, W0, B0)
    STAGE(1, W1, B1)
    STAGE(2, W2, B2)
    STAGE(3, W3, B3)
#undef STAGE
    __syncthreads();

    const unsigned lq = tid & 3u;
    const unsigned lane_p = tid >> 2;
    const unsigned l0 = lq << 2;
    const unsigned bs = blockIdx.x * pts_per_block;
    unsigned be = bs + pts_per_block;
    if (be > NPTS) be = NPTS;

    const unsigned Wk[4] = { W0, W1, W2, W3 };
    const unsigned Bk[4] = { B0, B1, B2, B3 };

    for (unsigned p = bs + lane_p; p < be; p += 64u) {
        float2 xy = x[p];
        vfloat4 r[2];

        if (lq == 0u) {
#pragma unroll
            for (int k = 0; k < 4; ++k) {
                float s = c_scale[k];
                float sx = xy.x * s, sy = xy.y * s;
                float fxf = floorf(sx), fyf = floorf(sy);
                float cxf = ceilf(sx),  cyf = ceilf(sy);
                float ox = sx - fxf, oy = sy - fyf;
                unsigned fx = (unsigned)(int)fxf, fy = (unsigned)(int)fyf;
                unsigned cx = (unsigned)(int)cxf, cy = (unsigned)(int)cyf;
                unsigned w = Wk[k], b = Bk[k];
                float2 f0 = lds[b + cy * w + cx];
                float2 f1 = lds[b + fy * w + cx];
                float2 f2 = lds[b + cy * w + fx];
                float2 f3 = lds[b + fy * w + fx];
                float wox = 1.0f - ox, woy = 1.0f - oy;
                float f03x = f0.x * ox + f3.x * wox;
                float f03y = f0.y * ox + f3.y * wox;
                float f12x = f1.x * ox + f2.x * wox;
                float f12y = f1.y * ox + f2.y * wox;
                float ex = f03x * oy + f12x * woy;
                float ey = f03y * oy + f12y * woy;
                if ((k & 1) == 0) { r[k >> 1].x = ex; r[k >> 1].y = ey; }
                else              { r[k >> 1].z = ex; r[k >> 1].w = ey; }
            }
        } else {
#pragma unroll
            for (int k = 0; k < 4; ++k) {
                float ex, ey;
                enc_level(xy, l0 + (unsigned)k, tab, ex, ey);
                if ((k & 1) == 0) { r[k >> 1].x = ex; r[k >> 1].y = ey; }
                else              { r[k >> 1].z = ex; r[k >> 1].w = ey; }
            }
        }

        unsigned o = p * 8u + lq * 2u;
        __builtin_nontemporal_store(r[0], &out[o]);
        __builtin_nontemporal_store(r[1], &out[o + 1]);
    }
}

extern "C" void kernel_launch(void* const* d_in, const int* in_sizes, int n_in,
                              void* d_out, int out_size, void* d_ws, size_t ws_size,
                              hipStream_t stream)
{
    const float2* x   = (const float2*)d_in[0];
    const float2* tab = (const float2*)d_in[1];
    vfloat4* out = (vfloat4*)d_out;

    if (d_ws != nullptr && ws_size >= (size_t)WS_NEED) {
        char* ws = (char*)d_ws;
        unsigned* cursor  = (unsigned*)(ws + WS_CURSOR);
        unsigned* ovf_cnt = (unsigned*)(ws + WS_OVFCNT);
        float2*   ovf_xy  = (float2*)  (ws + WS_OVF_XY);
        unsigned* ovf_idx = (unsigned*)(ws + WS_OVF_IDX);
        float2*   xybuf   = (float2*)  (ws + WS_XYBUF);
        unsigned* idxbuf  = (unsigned*)(ws + WS_IDXBUF);

        init_kernel<<<16, 256, 0, stream>>>(cursor, ovf_cnt);
        sort_kernel<<<256, 512, 0, stream>>>(x, cursor, ovf_cnt, ovf_xy,
                                             ovf_idx, xybuf, idxbuf);
        encode_kernel<<<NBUK / 8, 512, 0, stream>>>(xybuf, idxbuf, cursor, tab, out);
        fixup_kernel<<<8, 256, 0, stream>>>(ovf_cnt, ovf_xy, ovf_idx, tab, out);
    } else {
        const unsigned n_blocks = 1536u;
        const unsigned ppb = (NPTS + n_blocks - 1u) / n_blocks;
        hashenc_kernel<<<n_blocks, 256, 0, stream>>>(x, tab, out, ppb);
    }
}

// Round 9
// 254.680 us; speedup vs baseline: 1.2332x; 1.0889x over previous
//
#include <hip/hip_runtime.h>

#define TS 524288u          // 2^19
#define PRIME 2654435761u
#define NPTS 1048576u
#define MASK (TS - 1u)
#define NBUK 4096u          // 64x64 spatial buckets
#define CAP 320u            // bucket capacity: lambda=256, +4 sigma; overflow handled
#define OVF_CAP 8192u

// ---- ws layout (bytes); total 15.86 MB < 16.79 MB proven available ----
#define WS_CURSOR   0u          // u32[4096]          = 16384
#define WS_OVFCNT   16384u      // u32 (padded)
#define WS_OVF_XY   16640u      // float2[8192]       = 65536
#define WS_OVF_IDX  82176u      // u32[8192]          = 32768
#define WS_XYBUF    131072u     // float2[4096*320]   = 10485760
#define WS_IDXBUF   10616832u   // u32[4096*320]      = 5242880
#define WS_NEED     15859712u

typedef float vfloat4 __attribute__((ext_vector_type(4)));

// floor(16 * fl32(g)^l), g = 64^(1/15); fl32(g) rounds UP so the exact-integer
// levels (5,10,15) floor to 64/256/1024 under correctly-rounded powf (= numpy).
__device__ __constant__ float c_scale[16] = {
    16.f, 21.f, 27.f, 36.f, 48.f, 64.f, 84.f, 111.f,
    147.f, 194.f, 256.f, 337.f, 445.f, 588.f, 776.f, 1024.f
};

// Per-bucket per-level vertex-bbox LDS layout: W_l = ceil(scale_l/64)+2,
// entry = (base<<5) | W, base = prefix sum of W^2 (float2 units).
__device__ __constant__ unsigned c_lvl[16] = {
    (0u  <<5)|3u,  (9u  <<5)|3u,  (18u <<5)|3u,  (27u <<5)|3u,
    (36u <<5)|3u,  (45u <<5)|3u,  (54u <<5)|4u,  (70u <<5)|4u,
    (86u <<5)|5u,  (111u<<5)|6u,  (147u<<5)|6u,  (183u<<5)|8u,
    (247u<<5)|9u,  (328u<<5)|12u, (472u<<5)|15u, (697u<<5)|18u
};
#define BUKSTRIDE 1021u        // sum of W^2 = 697 + 324

// Legacy staged levels 0-3 (fallback kernel only).
#define W0 17
#define W1 22
#define W2 28
#define W3 37
#define B0 0
#define B1 (B0 + W0*W0)        // 289
#define B2 (B1 + W1*W1)        // 773
#define B3 (B2 + W2*W2)        // 1557
#define NSTAGE (B3 + W3*W3)    // 2926 float2 = 23408 B

__device__ __forceinline__ unsigned bucket_of(float2 xy) {
    unsigned bx = (unsigned)(xy.x * 64.0f); if (bx > 63u) bx = 63u;
    unsigned by = (unsigned)(xy.y * 64.0f); if (by > 63u) by = 63u;
    return by * 64u + bx;
}

// Shared bilinear tap: one level, global table (plain 4x float2 gathers).
__device__ __forceinline__ void enc_level(
    float2 xy, unsigned l, const float2* __restrict__ tab,
    float& ex, float& ey)
{
    float s = c_scale[l];
    float sx = xy.x * s, sy = xy.y * s;
    float fxf = floorf(sx), fyf = floorf(sy);
    float cxf = ceilf(sx),  cyf = ceilf(sy);
    float ox = sx - fxf, oy = sy - fyf;
    unsigned fx = (unsigned)(int)fxf, fy = (unsigned)(int)fyf;
    unsigned cx = (unsigned)(int)cxf, cy = (unsigned)(int)cyf;
    unsigned hcy = cy * PRIME, hfy = fy * PRIME;
    unsigned base = l << 19;
    float2 f0 = tab[((cx ^ hcy) & MASK) | base];
    float2 f1 = tab[((cx ^ hfy) & MASK) | base];
    float2 f2 = tab[((fx ^ hcy) & MASK) | base];
    float2 f3 = tab[((fx ^ hfy) & MASK) | base];
    float wox = 1.0f - ox, woy = 1.0f - oy;
    float f03x = f0.x * ox + f3.x * wox;
    float f03y = f0.y * ox + f3.y * wox;
    float f12x = f1.x * ox + f2.x * wox;
    float f12y = f1.y * ox + f2.y * wox;
    ex = f03x * oy + f12x * woy;
    ey = f03y * oy + f12y * woy;
}

// ---- Pass 0: init cursors (cursor[b] = b*CAP) + overflow counter ----
__global__ __launch_bounds__(256) void init_kernel(
    unsigned* __restrict__ cursor, unsigned* __restrict__ ovf_cnt)
{
    unsigned t = blockIdx.x * 256u + threadIdx.x;
    if (t < NBUK) cursor[t] = t * CAP;
    if (t == 0u) *ovf_cnt = 0u;
}

// ---- Pass 1: fused LDS-privatized counting sort (r8-proven, ~36us) ----
__global__ __launch_bounds__(512) void sort_kernel(
    const float2* __restrict__ x,
    unsigned* __restrict__ cursor,
    unsigned* __restrict__ ovf_cnt,
    float2* __restrict__ ovf_xy,
    unsigned* __restrict__ ovf_idx,
    float2* __restrict__ xybuf,
    unsigned* __restrict__ idxbuf)
{
    __shared__ unsigned lhist[NBUK];      // counts, then running local offsets
    __shared__ unsigned lbase_cap[NBUK];  // (reserved base << 9) | granted take
    unsigned tid = threadIdx.x;
    unsigned cbase = blockIdx.x * 4096u;

    for (unsigned j = tid; j < NBUK; j += 512u) lhist[j] = 0u;
    __syncthreads();

    float2 pxy[8];
#pragma unroll
    for (int k = 0; k < 8; ++k) {
        float2 xy = x[cbase + tid + (unsigned)k * 512u];
        pxy[k] = xy;
        atomicAdd(&lhist[bucket_of(xy)], 1u);
    }
    __syncthreads();

    for (unsigned j = tid; j < NBUK; j += 512u) {
        unsigned c = lhist[j];
        unsigned base = 0u, take = 0u;
        if (c) {
            base = atomicAdd(&cursor[j], c);
            unsigned prior = base - j * CAP;
            unsigned avail = (prior >= CAP) ? 0u : (CAP - prior);
            take = (c < avail) ? c : avail;
        }
        lbase_cap[j] = (base << 9) | take;
        lhist[j] = 0u;                 // reuse as running local offset
    }
    __syncthreads();

#pragma unroll
    for (int k = 0; k < 8; ++k) {
        float2 xy = pxy[k];
        unsigned b = bucket_of(xy);
        unsigned idx = cbase + tid + (unsigned)k * 512u;
        unsigned loff = atomicAdd(&lhist[b], 1u);
        unsigned bc = lbase_cap[b];
        unsigned take = bc & 511u;
        if (loff < take) {
            unsigned pos = (bc >> 9) + loff;
            xybuf[pos] = xy;
            idxbuf[pos] = idx;
        } else {
            unsigned o = atomicAdd(ovf_cnt, 1u);
            if (o < OVF_CAP) { ovf_xy[o] = xy; ovf_idx[o] = idx; }
        }
    }
}

// ---- Pass 2: encode, bucket-local LDS vertex cache.
// One wave per bucket. Stage every level's vertex bbox (1021 float2 = 8KB)
// into LDS once (~230 coalesced line-touches/bucket), then ALL bilerp taps
// are ds_read_b64 — the TA tag-lookup pipe (the measured invariant across
// r2/r8 nulls: ~28 line-touches/pt) is bypassed entirely.
// Coverage: float mul is monotone -> fx >= floor(fl(bx/64*s)) = x0 and
// cx <= floor(fl((bx+1)/64*s))+1 <= x0+W-1 for every in-bucket point. ----
__global__ __launch_bounds__(512) void encode_kernel(
    const float2* __restrict__ xybuf,
    const unsigned* __restrict__ idxbuf,
    const unsigned* __restrict__ cursor,
    const float2* __restrict__ tab,
    vfloat4* __restrict__ out)
{
    __shared__ float2 lds[8u * BUKSTRIDE];   // 65,344 B -> 2 blocks/CU
    unsigned tid  = threadIdx.x;
    unsigned wave = tid >> 6;
    unsigned lane = tid & 63u;
    unsigned b    = blockIdx.x * 8u + wave;
    unsigned bx   = b & 63u, by = b >> 6;
    float bxf = (float)bx * 0.015625f;       // bx/64, exact
    float byf = (float)by * 0.015625f;
    unsigned wbase = wave * BUKSTRIDE;

    // ---- stage this bucket's vertex bboxes, all 16 levels ----
    for (unsigned l = 0; l < 16u; ++l) {
        float s = c_scale[l];
        int x0 = (int)floorf(bxf * s);
        int y0 = (int)floorf(byf * s);
        unsigned u = c_lvl[l];
        unsigned W = u & 31u;
        unsigned base = wbase + (u >> 5);
        unsigned n = W * W;
        for (unsigned i = lane; i < n; i += 64u) {
            unsigned vy = (unsigned)(y0 + (int)(i / W));
            unsigned vx = (unsigned)(x0 + (int)(i % W));
            unsigned h = ((vx ^ (vy * PRIME)) & MASK) | (l << 19);
            lds[base + i] = tab[h];
        }
    }
    __syncthreads();

    unsigned lq = lane & 3u;             // level quad: levels 4lq..4lq+3
    unsigned s0 = lane >> 2;             // 0..15: slot within iteration
    unsigned l0 = lq << 2;
    unsigned total = cursor[b] - b * CAP;
    unsigned cnt = (total < CAP) ? total : CAP;
    unsigned pbase = b * CAP;

    for (unsigned s = s0; s < cnt; s += 16u) {
        float2 xy   = xybuf[pbase + s];
        unsigned idx = idxbuf[pbase + s];
        vfloat4 r[2];

#pragma unroll
        for (int k = 0; k < 4; ++k) {
            unsigned l = l0 + (unsigned)k;
            float sc = c_scale[l];
            float sx = xy.x * sc, sy = xy.y * sc;
            float fxf = floorf(sx), fyf = floorf(sy);
            float cxf = ceilf(sx),  cyf = ceilf(sy);
            float ox = sx - fxf, oy = sy - fyf;
            int x0 = (int)floorf(bxf * sc);
            int y0 = (int)floorf(byf * sc);
            unsigned lxf = (unsigned)((int)fxf - x0);
            unsigned lxc = (unsigned)((int)cxf - x0);
            unsigned lyf = (unsigned)((int)fyf - y0);
            unsigned lyc = (unsigned)((int)cyf - y0);
            unsigned u = c_lvl[l];
            unsigned W = u & 31u;
            unsigned base = wbase + (u >> 5);
            float2 f0 = lds[base + lyc * W + lxc];
            float2 f1 = lds[base + lyf * W + lxc];
            float2 f2 = lds[base + lyc * W + lxf];
            float2 f3 = lds[base + lyf * W + lxf];
            float wox = 1.0f - ox, woy = 1.0f - oy;
            float f03x = f0.x * ox + f3.x * wox;
            float f03y = f0.y * ox + f3.y * wox;
            float f12x = f1.x * ox + f2.x * wox;
            float f12y = f1.y * ox + f2.y * wox;
            float ex = f03x * oy + f12x * woy;
            float ey = f03y * oy + f12y * woy;
            if ((k & 1) == 0) { r[k >> 1].x = ex; r[k >> 1].y = ey; }
            else              { r[k >> 1].z = ex; r[k >> 1].w = ey; }
        }

        // 4 lq-threads of one point cover idx*8..idx*8+7: one aligned,
        // fully-written 128B record (2 lines) -> no write amplification.
        unsigned o = idx * 8u + lq * 2u;
        __builtin_nontemporal_store(r[0], &out[o]);
        __builtin_nontemporal_store(r[1], &out[o + 1]);
    }
}

// ---- Pass 3: encode overflow points directly (expected ~0-100 points) ----
__global__ __launch_bounds__(256) void fixup_kernel(
    const unsigned* __restrict__ ovf_cnt,
    const float2* __restrict__ ovf_xy,
    const unsigned* __restrict__ ovf_idx,
    const float2* __restrict__ tab,
    vfloat4* __restrict__ out)
{
    unsigned n = *ovf_cnt; if (n > OVF_CAP) n = OVF_CAP;
    unsigned stride = gridDim.x * 256u;
    for (unsigned p = blockIdx.x * 256u + threadIdx.x; p < n; p += stride) {
        float2 xy = ovf_xy[p];
        unsigned idx = ovf_idx[p];
        vfloat4 acc[8];
#pragma unroll
        for (int l = 0; l < 16; ++l) {
            float ex, ey;
            enc_level(xy, (unsigned)l, tab, ex, ey);
            if ((l & 1) == 0) { acc[l >> 1].x = ex; acc[l >> 1].y = ey; }
            else              { acc[l >> 1].z = ex; acc[l >> 1].w = ey; }
        }
#pragma unroll
        for (int q = 0; q < 8; ++q) out[idx * 8u + (unsigned)q] = acc[q];
    }
}

// ---- Fallback: proven round-0 unsorted kernel (ws too small; never expected) ----
__global__ __launch_bounds__(256) void hashenc_kernel(
    const float2* __restrict__ x,
    const float2* __restrict__ tab,
    vfloat4* __restrict__ out,
    unsigned pts_per_block)
{
    __shared__ float2 lds[NSTAGE];
    unsigned tid = threadIdx.x;

#define STAGE(L, W, B)                                                  \
    for (unsigned i = tid; i < (unsigned)((W)*(W)); i += 256u) {        \
        unsigned vy = i / (unsigned)(W), vx = i % (unsigned)(W);        \
        unsigned h = ((vx ^ (vy * PRIME)) & MASK) | ((unsigned)(L) << 19); \
        lds[(B) + i] = tab[h];                                          \
    }
    STAGE(0, W0, B0)
    STAGE(1, W1, B1)
    STAGE(2, W2, B2)
    STAGE(3, W3, B3)
#undef STAGE
    __syncthreads();

    const unsigned lq = tid & 3u;
    const unsigned lane_p = tid >> 2;
    const unsigned l0 = lq << 2;
    const unsigned bs = blockIdx.x * pts_per_block;
    unsigned be = bs + pts_per_block;
    if (be > NPTS) be = NPTS;

    const unsigned Wk[4] = { W0, W1, W2, W3 };
    const unsigned Bk[4] = { B0, B1, B2, B3 };

    for (unsigned p = bs + lane_p; p < be; p += 64u) {
        float2 xy = x[p];
        vfloat4 r[2];

        if (lq == 0u) {
#pragma unroll
            for (int k = 0; k < 4; ++k) {
                float s = c_scale[k];
                float sx = xy.x * s, sy = xy.y * s;
                float fxf = floorf(sx), fyf = floorf(sy);
                float cxf = ceilf(sx),  cyf = ceilf(sy);
                float ox = sx - fxf, oy = sy - fyf;
                unsigned fx = (unsigned)(int)fxf, fy = (unsigned)(int)fyf;
                unsigned cx = (unsigned)(int)cxf, cy = (unsigned)(int)cyf;
                unsigned w = Wk[k], b = Bk[k];
                float2 f0 = lds[b + cy * w + cx];
                float2 f1 = lds[b + fy * w + cx];
                float2 f2 = lds[b + cy * w + fx];
                float2 f3 = lds[b + fy * w + fx];
                float wox = 1.0f - ox, woy = 1.0f - oy;
                float f03x = f0.x * ox + f3.x * wox;
                float f03y = f0.y * ox + f3.y * wox;
                float f12x = f1.x * ox + f2.x * wox;
                float f12y = f1.y * ox + f2.y * wox;
                float ex = f03x * oy + f12x * woy;
                float ey = f03y * oy + f12y * woy;
                if ((k & 1) == 0) { r[k >> 1].x = ex; r[k >> 1].y = ey; }
                else              { r[k >> 1].z = ex; r[k >> 1].w = ey; }
            }
        } else {
#pragma unroll
            for (int k = 0; k < 4; ++k) {
                float ex, ey;
                enc_level(xy, l0 + (unsigned)k, tab, ex, ey);
                if ((k & 1) == 0) { r[k >> 1].x = ex; r[k >> 1].y = ey; }
                else              { r[k >> 1].z = ex; r[k >> 1].w = ey; }
            }
        }

        unsigned o = p * 8u + lq * 2u;
        __builtin_nontemporal_store(r[0], &out[o]);
        __builtin_nontemporal_store(r[1], &out[o + 1]);
    }
}

extern "C" void kernel_launch(void* const* d_in, const int* in_sizes, int n_in,
                              void* d_out, int out_size, void* d_ws, size_t ws_size,
                              hipStream_t stream)
{
    const float2* x   = (const float2*)d_in[0];
    const float2* tab = (const float2*)d_in[1];
    vfloat4* out = (vfloat4*)d_out;

    if (d_ws != nullptr && ws_size >= (size_t)WS_NEED) {
        char* ws = (char*)d_ws;
        unsigned* cursor  = (unsigned*)(ws + WS_CURSOR);
        unsigned* ovf_cnt = (unsigned*)(ws + WS_OVFCNT);
        float2*   ovf_xy  = (float2*)  (ws + WS_OVF_XY);
        unsigned* ovf_idx = (unsigned*)(ws + WS_OVF_IDX);
        float2*   xybuf   = (float2*)  (ws + WS_XYBUF);
        unsigned* idxbuf  = (unsigned*)(ws + WS_IDXBUF);

        init_kernel<<<16, 256, 0, stream>>>(cursor, ovf_cnt);
        sort_kernel<<<256, 512, 0, stream>>>(x, cursor, ovf_cnt, ovf_xy,
                                             ovf_idx, xybuf, idxbuf);
        encode_kernel<<<NBUK / 8, 512, 0, stream>>>(xybuf, idxbuf, cursor, tab, out);
        fixup_kernel<<<8, 256, 0, stream>>>(ovf_cnt, ovf_xy, ovf_idx, tab, out);
    } else {
        const unsigned n_blocks = 1536u;
        const unsigned ppb = (NPTS + n_blocks - 1u) / n_blocks;
        hashenc_kernel<<<n_blocks, 256, 0, stream>>>(x, tab, out, ppb);
    }
}